// Round 1
// baseline (1933.818 us; speedup 1.0000x reference)
//
#include <hip/hip_runtime.h>
#include <hip/hip_bf16.h>
#include <stdint.h>

// Problem constants (fixed by the reference)
#define TOKENS 8192
#define IN_F   4096
#define OUT_F  16384

typedef __bf16 bf16;
typedef __bf16 bf16x8 __attribute__((ext_vector_type(8)));
typedef float  f32x4  __attribute__((ext_vector_type(4)));

__device__ __constant__ float NF4[16] = {
    -1.0f, -0.6961928009986877f, -0.5250730514526367f, -0.39491748809814453f,
    -0.28444138169288635f, -0.18477343022823334f, -0.09105003625154495f, 0.0f,
    0.07958029955625534f, 0.16093020141124725f, 0.24611230194568634f,
    0.33791524171829224f, 0.44070982933044434f, 0.5626170039176941f,
    0.7229568362236023f, 1.0f};

// ---------- x fp32 -> bf16 ----------
__global__ __launch_bounds__(256) void cvt_kernel(const float* __restrict__ x,
                                                  bf16* __restrict__ xb) {
    size_t base = ((size_t)blockIdx.x * blockDim.x + threadIdx.x) * 8;
    float4 a = *(const float4*)(x + base);
    float4 b = *(const float4*)(x + base + 4);
    bf16x8 w;
    w[0] = (bf16)a.x; w[1] = (bf16)a.y; w[2] = (bf16)a.z; w[3] = (bf16)a.w;
    w[4] = (bf16)b.x; w[5] = (bf16)b.y; w[6] = (bf16)b.z; w[7] = (bf16)b.w;
    *(bf16x8*)(xb + base) = w;
}

// ---------- NF4 dequant: codes(int32)+absmax -> W bf16 [OUT_F][IN_F] ----------
__global__ __launch_bounds__(256) void dequant_kernel(const int* __restrict__ codes,
                                                      const float* __restrict__ absmax,
                                                      bf16* __restrict__ W) {
    __shared__ float lut[16];
    if (threadIdx.x < 16) lut[threadIdx.x] = NF4[threadIdx.x];
    __syncthreads();
    size_t base = ((size_t)blockIdx.x * blockDim.x + threadIdx.x) * 8;
    float scale = absmax[base >> 6];   // 8 consecutive elems share one 64-block
    int4 c0 = *(const int4*)(codes + base);
    int4 c1 = *(const int4*)(codes + base + 4);
    bf16x8 w;
    w[0] = (bf16)(lut[c0.x] * scale);
    w[1] = (bf16)(lut[c0.y] * scale);
    w[2] = (bf16)(lut[c0.z] * scale);
    w[3] = (bf16)(lut[c0.w] * scale);
    w[4] = (bf16)(lut[c1.x] * scale);
    w[5] = (bf16)(lut[c1.y] * scale);
    w[6] = (bf16)(lut[c1.z] * scale);
    w[7] = (bf16)(lut[c1.w] * scale);
    *(bf16x8*)(W + base) = w;
}

// ---------- m97-style bf16 GEMM, B^T layout ----------
#define BM 128
#define BN 128
#define BK 32

typedef const unsigned int __attribute__((address_space(1)))* gas_ptr;
typedef unsigned int __attribute__((address_space(3)))* las_ptr;

__device__ __forceinline__ void async_load16(const void* g, void* l) {
    __builtin_amdgcn_global_load_lds((gas_ptr)(uintptr_t)g, (las_ptr)(uintptr_t)l, 16, 0, 0);
}

__global__ __launch_bounds__(256) void gemm_bt(const bf16* __restrict__ A,   // [M][K]
                                               const bf16* __restrict__ B,   // [N][K]
                                               const float* __restrict__ bias,
                                               float* __restrict__ C) {     // [M][N]
    constexpr int M = TOKENS, N = OUT_F, K = IN_F;
    (void)M;
    __shared__ bf16 As[BM * BK];
    __shared__ bf16 Bs[BN * BK];

    const int t = threadIdx.x;
    const int wave = t >> 6, lane = t & 63;
    const int quad = lane >> 4, r16 = lane & 15;
    const int wr = wave >> 1, wc = wave & 1;          // 2x2 waves -> 64x64 quadrants
    const int m0 = blockIdx.y * BM;
    const int n0 = blockIdx.x * BN;

    f32x4 acc[4][4];
#pragma unroll
    for (int i = 0; i < 4; i++)
#pragma unroll
        for (int j = 0; j < 4; j++) acc[i][j] = (f32x4){0.f, 0.f, 0.f, 0.f};

    // staging geometry: 512 chunks of 16B per 128x32 tile, chunk c -> row c>>2, col8 (c&3)*8
    const int c0r = t >> 2, c0c = (t & 3) * 8;
    const int c1r = (256 + t) >> 2, c1c = ((256 + t) & 3) * 8;
    bf16* lA0 = As + (size_t)(wave * 64) * 8;
    bf16* lA1 = As + (size_t)(256 + wave * 64) * 8;
    bf16* lB0 = Bs + (size_t)(wave * 64) * 8;
    bf16* lB1 = Bs + (size_t)(256 + wave * 64) * 8;
    const bf16* gA = A + (size_t)m0 * K;
    const bf16* gB = B + (size_t)n0 * K;

    for (int k0 = 0; k0 < K; k0 += BK) {
        async_load16(gA + (size_t)c0r * K + k0 + c0c, lA0);
        async_load16(gA + (size_t)c1r * K + k0 + c1c, lA1);
        async_load16(gB + (size_t)c0r * K + k0 + c0c, lB0);
        async_load16(gB + (size_t)c1r * K + k0 + c1c, lB1);
        __syncthreads();   // compiler emits s_waitcnt vmcnt(0) before s_barrier

        bf16x8 af[4], bfr[4];
#pragma unroll
        for (int i = 0; i < 4; i++)
            af[i] = *(const bf16x8*)(As + (wr * 64 + i * 16 + r16) * BK + quad * 8);
#pragma unroll
        for (int j = 0; j < 4; j++)
            bfr[j] = *(const bf16x8*)(Bs + (wc * 64 + j * 16 + r16) * BK + quad * 8);

#pragma unroll
        for (int i = 0; i < 4; i++)
#pragma unroll
            for (int j = 0; j < 4; j++)
                acc[i][j] = __builtin_amdgcn_mfma_f32_16x16x32_bf16(af[i], bfr[j], acc[i][j], 0, 0, 0);
        __syncthreads();
    }

    // epilogue: C/D layout col=lane&15, row=quad*4+reg
    float bj[4];
#pragma unroll
    for (int j = 0; j < 4; j++) bj[j] = bias[n0 + wc * 64 + j * 16 + r16];
#pragma unroll
    for (int i = 0; i < 4; i++) {
#pragma unroll
        for (int r = 0; r < 4; r++) {
            int m = m0 + wr * 64 + i * 16 + quad * 4 + r;
            float* crow = C + (size_t)m * N + n0 + wc * 64 + r16;
#pragma unroll
            for (int j = 0; j < 4; j++) crow[j * 16] = acc[i][j][r] + bj[j];
        }
    }
}

// ---------- correctness fallback if workspace too small ----------
#define FT 16
__global__ void gemm_fallback(const float* __restrict__ x, const int* __restrict__ codes,
                              const float* __restrict__ absmax, const float* __restrict__ bias,
                              float* __restrict__ C) {
    __shared__ float xs[FT][FT];
    __shared__ float ws_[FT][FT + 1];
    int tx = threadIdx.x, ty = threadIdx.y;
    int n = blockIdx.x * FT + tx;
    int m = blockIdx.y * FT + ty;
    float acc = 0.f;
    for (int k0 = 0; k0 < IN_F; k0 += FT) {
        xs[ty][tx] = x[(size_t)m * IN_F + k0 + tx];
        int o = blockIdx.x * FT + ty;
        size_t widx = (size_t)o * IN_F + k0 + tx;
        ws_[ty][tx] = NF4[codes[widx]] * absmax[widx >> 6];
        __syncthreads();
#pragma unroll
        for (int k = 0; k < FT; k++) acc += xs[ty][k] * ws_[tx][k];
        __syncthreads();
    }
    C[(size_t)m * OUT_F + n] = acc + bias[n];
}

extern "C" void kernel_launch(void* const* d_in, const int* in_sizes, int n_in,
                              void* d_out, int out_size, void* d_ws, size_t ws_size,
                              hipStream_t stream) {
    const float* x      = (const float*)d_in[0];
    const int*   codes  = (const int*)d_in[1];
    const float* absmax = (const float*)d_in[2];
    const float* bias   = (const float*)d_in[3];
    float* out = (float*)d_out;

    const size_t xb_elems = (size_t)TOKENS * IN_F;
    const size_t w_elems  = (size_t)OUT_F * IN_F;
    const size_t need = (xb_elems + w_elems) * sizeof(bf16);

    if (ws_size >= need) {
        bf16* xb = (bf16*)d_ws;
        bf16* W  = xb + xb_elems;
        cvt_kernel<<<(int)(xb_elems / 8 / 256), 256, 0, stream>>>(x, xb);
        dequant_kernel<<<(int)(w_elems / 8 / 256), 256, 0, stream>>>(codes, absmax, W);
        gemm_bt<<<dim3(OUT_F / BN, TOKENS / BM), 256, 0, stream>>>(xb, W, bias, out);
    } else {
        gemm_fallback<<<dim3(OUT_F / FT, TOKENS / FT), dim3(FT, FT), 0, stream>>>(
            x, codes, absmax, bias, out);
    }
}